// Round 2
// baseline (102.146 us; speedup 1.0000x reference)
//
#include <hip/hip_runtime.h>

#define BS 128
#define T 256
#define D 1024
#define NCAT 2688
#define NLOC 128
#define NFEAT 1024

typedef short bf16x8 __attribute__((ext_vector_type(8)));
typedef float f32x4 __attribute__((ext_vector_type(4)));
typedef unsigned short u16;
typedef u16 u16x4 __attribute__((ext_vector_type(4)));

__device__ __forceinline__ u16 f2bf(float f) {
    unsigned int u = __float_as_uint(f);
    u += 0x7fffu + ((u >> 16) & 1u);   // round-to-nearest-even
    return (u16)(u >> 16);
}

// ---------------------------------------------------------------------------
// K0: per-batch v_len, s, e.
// ---------------------------------------------------------------------------
__global__ void k0_prep(const int* __restrict__ vmask, const float* __restrict__ loc,
                        int* __restrict__ vlen, int* __restrict__ sArr, int* __restrict__ eArr) {
    int b = blockIdx.x, tid = threadIdx.x;   // 128 x 256
    __shared__ int red[256];
    red[tid] = vmask[b * T + tid];
    __syncthreads();
    for (int off = 128; off > 0; off >>= 1) {
        if (tid < off) red[tid] += red[tid + off];
        __syncthreads();
    }
    if (tid == 0) {
        int vl = red[0];
        vlen[b] = vl;
        float sc = (float)(vl - 1);
        sArr[b] = (int)floorf(loc[2 * b] * sc);
        eArr[b] = (int)floorf(loc[2 * b + 1] * sc);
    }
}

// ---------------------------------------------------------------------------
// KW: convert W1, W2, W4 (f32) -> bf16 scratch copies. One float4 per thread.
// n1/4=131072, n2/4=131072, n4/4=688128; total 950272 = 3712 * 256.
// ---------------------------------------------------------------------------
__global__ void kw_conv(const float* __restrict__ W1, const float* __restrict__ W2,
                        const float* __restrict__ W4,
                        u16* __restrict__ W1b, u16* __restrict__ W2b, u16* __restrict__ W4b) {
    int i = blockIdx.x * 256 + threadIdx.x;   // float4 index
    const float* src;
    u16* dst;
    if (i < 131072)       { src = W1 + 4 * i;               dst = W1b + 4 * i; }
    else if (i < 262144)  { src = W2 + 4 * (i - 131072);    dst = W2b + 4 * (i - 131072); }
    else                  { src = W4 + 4 * (i - 262144);    dst = W4b + 4 * (i - 262144); }
    f32x4 v = *(const f32x4*)src;
    u16x4 o;
#pragma unroll
    for (int j = 0; j < 4; ++j) o[j] = f2bf(v[j]);
    *(u16x4*)dst = o;
}

// ---------------------------------------------------------------------------
// K1: fused visual_fea copy (f32, byte-exact) + masked mean partials + segment
// partials. grid = 128 b x 8 t-chunks (32 t each), 256 threads x float4.
// ---------------------------------------------------------------------------
__global__ void k1_copy_pool(const float* __restrict__ vf, float* __restrict__ out0,
                             const int* __restrict__ vlen, const int* __restrict__ sArr,
                             const int* __restrict__ eArr,
                             float* __restrict__ pgv, float* __restrict__ pseg) {
    int b  = blockIdx.x >> 3;
    int tc = blockIdx.x & 7;
    int tid = threadIdx.x;          // 0..255
    int d0 = tid * 4;
    int vl = vlen[b], s = sArr[b], e = eArr[b];

    f32x4 g  = {0.f, 0.f, 0.f, 0.f};
    f32x4 sg = {0.f, 0.f, 0.f, 0.f};

    const float* src = vf   + ((size_t)(b * T + tc * 32)) * D + d0;
    float*       dst = out0 + ((size_t)(b * T + tc * 32)) * D + d0;

    for (int i = 0; i < 32; ++i) {
        f32x4 v = *(const f32x4*)src;
        *(f32x4*)dst = v;
        int t = tc * 32 + i;
        if (t < vl) g += v;
        if (t >= s && t <= e) sg += v;
        src += D; dst += D;
    }
    int o = (b * 8 + tc) * D + d0;
    *(f32x4*)(pgv  + o) = g;
    *(f32x4*)(pseg + o) = sg;
}

// ---------------------------------------------------------------------------
// K2: reduce partials -> gv_fea / lv_fea (bf16 into cat / lv), sen_fea -> cat
// (bf16) + out1 (f32 exact), loc_fea head -> cat.
// cat layout: [sen 0..1023 | gv 1024..2047 | vs 2048..2559 | loc 2560..2687]
// ---------------------------------------------------------------------------
__global__ void k2_build(const float* __restrict__ sen_fea, const float* __restrict__ loc,
                         const float* __restrict__ W3, const float* __restrict__ b3,
                         const int* __restrict__ vlen, const int* __restrict__ sArr,
                         const int* __restrict__ eArr,
                         const float* __restrict__ pgv, const float* __restrict__ pseg,
                         u16* __restrict__ lv_bf, u16* __restrict__ cat, float* __restrict__ out1) {
    int b = blockIdx.x, tid = threadIdx.x;   // 128 x 256
    int vl = vlen[b], s = sArr[b], e = eArr[b];
    float inv_vl = 1.0f / (float)vl;
    int cnt = e + 1 - s; if (cnt < 1) cnt = 1;
    float inv_cnt = 1.0f / (float)cnt;
    bool valid = (s <= e);

    for (int d = tid; d < D; d += 256) {
        float gs = 0.f, ss = 0.f;
#pragma unroll
        for (int c = 0; c < 8; ++c) {
            gs += pgv [(b * 8 + c) * D + d];
            ss += pseg[(b * 8 + c) * D + d];
        }
        cat[b * NCAT + 1024 + d] = f2bf(gs * inv_vl);
        lv_bf[b * D + d] = f2bf(valid ? ss * inv_cnt : 0.f);
        float sf = sen_fea[b * D + d];
        cat[b * NCAT + d] = f2bf(sf);
        out1[b * D + d] = sf;
    }
    if (tid < NLOC) {
        float v = loc[2 * b] * W3[2 * tid] + loc[2 * b + 1] * W3[2 * tid + 1] + b3[tid];
        cat[b * NCAT + 2560 + tid] = f2bf(fmaxf(v, 0.f));
    }
}

// ---------------------------------------------------------------------------
// K3: vs = relu((lv @ W1^T + b1) * (sen @ W2^T + b2)) -> cat[2048..2559] (bf16)
// M=128, N=512, K=1024. 64 blocks x 4 waves, 16x16 tile per wave.
// ---------------------------------------------------------------------------
__global__ void k3_vs(const u16* __restrict__ lv, const u16* __restrict__ catsen,
                      const u16* __restrict__ W1b, const float* __restrict__ b1,
                      const u16* __restrict__ W2b, const float* __restrict__ b2,
                      u16* __restrict__ cat) {
    int wid = threadIdx.x >> 6, lane = threadIdx.x & 63;
    int mt = blockIdx.x >> 3, ntg = blockIdx.x & 7;
    int nt = ntg * 4 + wid;
    int m0 = mt * 16, n0 = nt * 16;
    int row = lane & 15, kg = lane >> 4;

    f32x4 accP = {0.f, 0.f, 0.f, 0.f};
    f32x4 accQ = {0.f, 0.f, 0.f, 0.f};

    const u16* pa1 = lv     + (m0 + row) * 1024 + kg * 8;
    const u16* pa2 = catsen + (m0 + row) * NCAT + kg * 8;  // sen_fea = cat[:,0:1024]
    const u16* pb1 = W1b    + (n0 + row) * 1024 + kg * 8;
    const u16* pb2 = W2b    + (n0 + row) * 1024 + kg * 8;

    for (int k = 0; k < 1024; k += 32) {
        bf16x8 a1 = *(const bf16x8*)(pa1 + k);
        bf16x8 a2 = *(const bf16x8*)(pa2 + k);
        bf16x8 w1 = *(const bf16x8*)(pb1 + k);
        bf16x8 w2 = *(const bf16x8*)(pb2 + k);
        accP = __builtin_amdgcn_mfma_f32_16x16x32_bf16(a1, w1, accP, 0, 0, 0);
        accQ = __builtin_amdgcn_mfma_f32_16x16x32_bf16(a2, w2, accQ, 0, 0, 0);
    }
    int col = lane & 15, rbase = (lane >> 4) * 4;
    float bb1 = b1[n0 + col], bb2 = b2[n0 + col];
#pragma unroll
    for (int r = 0; r < 4; ++r) {
        int m = m0 + rbase + r;
        float p = accP[r] + bb1;
        float q = accQ[r] + bb2;
        cat[m * NCAT + 2048 + n0 + col] = f2bf(fmaxf(p * q, 0.f));
    }
}

// ---------------------------------------------------------------------------
// K4: feature = relu(cat @ W4^T + b4) -> out2 (f32). M=128, N=1024, K=2688.
// 128 blocks x 4 waves, 16x16 tile per wave.
// ---------------------------------------------------------------------------
__global__ void k4_feat(const u16* __restrict__ cat, const u16* __restrict__ W4b,
                        const float* __restrict__ b4, float* __restrict__ out2) {
    int wid = threadIdx.x >> 6, lane = threadIdx.x & 63;
    int mt = blockIdx.x >> 4, ntg = blockIdx.x & 15;
    int nt = ntg * 4 + wid;            // 0..63
    int m0 = mt * 16, n0 = nt * 16;
    int row = lane & 15, kg = lane >> 4;

    f32x4 acc = {0.f, 0.f, 0.f, 0.f};
    const u16* pa = cat + (m0 + row) * NCAT + kg * 8;
    const u16* pb = W4b + (n0 + row) * NCAT + kg * 8;

    for (int k = 0; k < NCAT; k += 32) {
        bf16x8 a = *(const bf16x8*)(pa + k);
        bf16x8 w = *(const bf16x8*)(pb + k);
        acc = __builtin_amdgcn_mfma_f32_16x16x32_bf16(a, w, acc, 0, 0, 0);
    }
    int col = lane & 15, rbase = (lane >> 4) * 4;
    float bb = b4[n0 + col];
#pragma unroll
    for (int r = 0; r < 4; ++r) {
        int m = m0 + rbase + r;
        out2[m * NFEAT + n0 + col] = fmaxf(acc[r] + bb, 0.f);
    }
}

// ---------------------------------------------------------------------------
extern "C" void kernel_launch(void* const* d_in, const int* in_sizes, int n_in,
                              void* d_out, int out_size, void* d_ws, size_t ws_size,
                              hipStream_t stream) {
    (void)in_sizes; (void)n_in; (void)out_size; (void)ws_size;
    // input order: step, gv, sen, visual_fea, sen_fea, loc, sen_mask, video_mask,
    //              W1, b1, W2, b2, W3, b3, W4, b4   (all floats are f32)
    const float* vf      = (const float*)d_in[3];
    const float* sen_fea = (const float*)d_in[4];
    const float* loc     = (const float*)d_in[5];
    const int*   vmask   = (const int*)d_in[7];
    const float* W1 = (const float*)d_in[8];
    const float* b1 = (const float*)d_in[9];
    const float* W2 = (const float*)d_in[10];
    const float* b2 = (const float*)d_in[11];
    const float* W3 = (const float*)d_in[12];
    const float* b3 = (const float*)d_in[13];
    const float* W4 = (const float*)d_in[14];
    const float* b4 = (const float*)d_in[15];

    float* out0 = (float*)d_out;                 // visual_fea copy: 128*256*1024
    float* out1 = out0 + (size_t)BS * T * D;     // sen_fea copy:    128*1024
    float* out2 = out1 + (size_t)BS * D;         // feature:         128*1024

    // workspace carve (byte offsets, all 16B-aligned)
    char* w = (char*)d_ws;
    int*   vlen = (int*)(w + 0);
    int*   sArr = (int*)(w + 512);
    int*   eArr = (int*)(w + 1024);
    float* pgv  = (float*)(w + 4096);                         // 128*8*1024 f32 = 4 MB
    float* pseg = (float*)(w + 4096 + 4194304);               // 4 MB
    u16*   cat  = (u16*)  (w + 4096 + 2 * 4194304);           // 128*2688 bf16 = 688128 B
    u16*   lv   = (u16*)  (w + 4096 + 2 * 4194304 + 688128);  // 128*1024 bf16 = 262144 B
    u16*   W1b  = (u16*)  (w + 4096 + 2 * 4194304 + 950272);  // 1 MB
    u16*   W2b  = (u16*)  (w + 4096 + 2 * 4194304 + 950272 + 1048576);
    u16*   W4b  = (u16*)  (w + 4096 + 2 * 4194304 + 950272 + 2097152);  // 5.25 MB

    k0_prep<<<BS, 256, 0, stream>>>(vmask, loc, vlen, sArr, eArr);
    kw_conv<<<3712, 256, 0, stream>>>(W1, W2, W4, W1b, W2b, W4b);
    k1_copy_pool<<<BS * 8, 256, 0, stream>>>(vf, out0, vlen, sArr, eArr, pgv, pseg);
    k2_build<<<BS, 256, 0, stream>>>(sen_fea, loc, W3, b3, vlen, sArr, eArr,
                                     pgv, pseg, lv, cat, out1);
    k3_vs<<<64, 256, 0, stream>>>(lv, cat, W1b, b1, W2b, b2, cat);
    k4_feat<<<128, 256, 0, stream>>>(cat, W4b, b4, out2);
}

// Round 3
// 71.079 us; speedup vs baseline: 1.4371x; 1.4371x over previous
//
#include <hip/hip_runtime.h>

#define BS 128
#define T 256
#define D 1024
#define NCAT 2688
#define NLOC 128
#define NFEAT 1024

typedef short bf16x8 __attribute__((ext_vector_type(8)));
typedef float f32x4 __attribute__((ext_vector_type(4)));
typedef unsigned short u16;
typedef u16 u16x4 __attribute__((ext_vector_type(4)));

__device__ __forceinline__ u16 f2bf(float f) {
    unsigned int u = __float_as_uint(f);
    u += 0x7fffu + ((u >> 16) & 1u);   // round-to-nearest-even
    return (u16)(u >> 16);
}

// ---------------------------------------------------------------------------
// KA: blocks [0,1024): fused visual_fea copy + masked/segment pooling partials
//     (vlen/s/e derived in-block from video_mask -> no k0 dependency).
//     blocks [1024,4736): f32->bf16 conversion of W1,W2,W4 (independent work
//     that backfills spare occupancy while the copy saturates HBM).
// ---------------------------------------------------------------------------
__global__ void ka_copy_pool_w(const float* __restrict__ vf, float* __restrict__ out0,
                               const int* __restrict__ vmask, const float* __restrict__ loc,
                               const float* __restrict__ W1, const float* __restrict__ W2,
                               const float* __restrict__ W4,
                               u16* __restrict__ W1b, u16* __restrict__ W2b,
                               u16* __restrict__ W4b,
                               float* __restrict__ pgv, float* __restrict__ pseg) {
    int blk = blockIdx.x, tid = threadIdx.x;

    if (blk >= 1024) {                       // ---- weight conversion ----
        int i = (blk - 1024) * 256 + tid;    // float4 index, 950272 total
        const float* src; u16* dst;
        if (i < 131072)      { src = W1 + 4 * i;            dst = W1b + 4 * i; }
        else if (i < 262144) { src = W2 + 4 * (i - 131072); dst = W2b + 4 * (i - 131072); }
        else                 { src = W4 + 4 * (i - 262144); dst = W4b + 4 * (i - 262144); }
        f32x4 v = *(const f32x4*)src;
        u16x4 o;
#pragma unroll
        for (int j = 0; j < 4; ++j) o[j] = f2bf(v[j]);
        *(u16x4*)dst = o;
        return;
    }

    // ---- copy + pool ----
    int b = blk >> 3, tc = blk & 7;
    __shared__ int red[256];
    __shared__ int sse[3];
    red[tid] = vmask[b * T + tid];
    __syncthreads();
    for (int off = 128; off > 0; off >>= 1) {
        if (tid < off) red[tid] += red[tid + off];
        __syncthreads();
    }
    if (tid == 0) {
        int vl = red[0];
        float sc = (float)(vl - 1);
        sse[0] = vl;
        sse[1] = (int)floorf(loc[2 * b] * sc);
        sse[2] = (int)floorf(loc[2 * b + 1] * sc);
    }
    __syncthreads();
    int vl = sse[0], s = sse[1], e = sse[2];

    int d0 = tid * 4;
    f32x4 g  = {0.f, 0.f, 0.f, 0.f};
    f32x4 sg = {0.f, 0.f, 0.f, 0.f};
    const float* src = vf   + ((size_t)(b * T + tc * 32)) * D + d0;
    float*       dst = out0 + ((size_t)(b * T + tc * 32)) * D + d0;

    for (int i = 0; i < 32; ++i) {
        f32x4 v = *(const f32x4*)src;
        __builtin_nontemporal_store(v, (f32x4*)dst);   // streaming, keep L2 clean
        int t = tc * 32 + i;
        if (t < vl) g += v;
        if (t >= s && t <= e) sg += v;
        src += D; dst += D;
    }
    int o = (b * 8 + tc) * D + d0;
    *(f32x4*)(pgv  + o) = g;
    *(f32x4*)(pseg + o) = sg;
}

// ---------------------------------------------------------------------------
// K2: reduce partials -> gv_fea / lv_fea; build cat + out1; loc_fea head.
// vlen/s/e re-derived in-block. cat layout:
// [sen 0..1023 | gv 1024..2047 | vs 2048..2559 | loc 2560..2687]
// ---------------------------------------------------------------------------
__global__ void k2_build(const float* __restrict__ sen_fea, const float* __restrict__ loc,
                         const float* __restrict__ W3, const float* __restrict__ b3,
                         const int* __restrict__ vmask,
                         const float* __restrict__ pgv, const float* __restrict__ pseg,
                         u16* __restrict__ lv_bf, u16* __restrict__ cat,
                         float* __restrict__ out1) {
    int b = blockIdx.x, tid = threadIdx.x;   // 128 x 256
    __shared__ int red[256];
    __shared__ int sse[3];
    red[tid] = vmask[b * T + tid];
    __syncthreads();
    for (int off = 128; off > 0; off >>= 1) {
        if (tid < off) red[tid] += red[tid + off];
        __syncthreads();
    }
    if (tid == 0) {
        int vl = red[0];
        float sc = (float)(vl - 1);
        sse[0] = vl;
        sse[1] = (int)floorf(loc[2 * b] * sc);
        sse[2] = (int)floorf(loc[2 * b + 1] * sc);
    }
    __syncthreads();
    int vl = sse[0], s = sse[1], e = sse[2];

    float inv_vl = 1.0f / (float)vl;
    int cnt = e + 1 - s; if (cnt < 1) cnt = 1;
    float inv_cnt = 1.0f / (float)cnt;
    bool valid = (s <= e);

    for (int d = tid; d < D; d += 256) {
        float gs = 0.f, ss = 0.f;
#pragma unroll
        for (int c = 0; c < 8; ++c) {
            gs += pgv [(b * 8 + c) * D + d];
            ss += pseg[(b * 8 + c) * D + d];
        }
        cat[b * NCAT + 1024 + d] = f2bf(gs * inv_vl);
        lv_bf[b * D + d] = f2bf(valid ? ss * inv_cnt : 0.f);
        float sf = sen_fea[b * D + d];
        cat[b * NCAT + d] = f2bf(sf);
        out1[b * D + d] = sf;
    }
    if (tid < NLOC) {
        float v = loc[2 * b] * W3[2 * tid] + loc[2 * b + 1] * W3[2 * tid + 1] + b3[tid];
        cat[b * NCAT + 2560 + tid] = f2bf(fmaxf(v, 0.f));
    }
}

// ---------------------------------------------------------------------------
// K3: vs = relu((lv@W1^T+b1)*(sen@W2^T+b2)) -> cat[2048..2559]
// 256 blocks x 2 waves: wave0 = P chain, wave1 = Q chain, same-lane LDS swap.
// ---------------------------------------------------------------------------
__global__ void k3_vs(const u16* __restrict__ lv, const u16* __restrict__ cat_ro,
                      const u16* __restrict__ W1b, const float* __restrict__ b1,
                      const u16* __restrict__ W2b, const float* __restrict__ b2,
                      u16* __restrict__ cat) {
    int wid = threadIdx.x >> 6, lane = threadIdx.x & 63;
    int mt = blockIdx.x >> 5, nt = blockIdx.x & 31;   // 8 x 32 tiles of 16x16
    int m0 = mt * 16, n0 = nt * 16;
    int row = lane & 15, kg = lane >> 4;

    const u16* pa = (wid == 0) ? (lv + (m0 + row) * D + kg * 8)
                               : (cat_ro + (m0 + row) * NCAT + kg * 8);  // sen cols 0..1023
    const u16* pb = ((wid == 0) ? W1b : W2b) + (n0 + row) * D + kg * 8;

    f32x4 acc = {0.f, 0.f, 0.f, 0.f};
    for (int k = 0; k < 1024; k += 32)
        acc = __builtin_amdgcn_mfma_f32_16x16x32_bf16(*(const bf16x8*)(pa + k),
                                                      *(const bf16x8*)(pb + k), acc, 0, 0, 0);

    int col = lane & 15, rbase = (lane >> 4) * 4;
    float bb = ((wid == 0) ? b1 : b2)[n0 + col];

    __shared__ float qs[4][64];
    if (wid == 1) {
#pragma unroll
        for (int r = 0; r < 4; ++r) qs[r][lane] = acc[r] + bb;
    }
    __syncthreads();
    if (wid == 0) {
#pragma unroll
        for (int r = 0; r < 4; ++r) {
            float p = acc[r] + bb;
            cat[(m0 + rbase + r) * NCAT + 2048 + n0 + col] = f2bf(fmaxf(p * qs[r][lane], 0.f));
        }
    }
}

// ---------------------------------------------------------------------------
// K4: feature = relu(cat @ W4^T + b4) -> out2 (f32). M=128,N=1024,K=2688.
// 512 blocks x 2 waves, split-K=2 (1344 each), same-lane LDS reduce.
// ---------------------------------------------------------------------------
__global__ void k4_feat(const u16* __restrict__ cat, const u16* __restrict__ W4b,
                        const float* __restrict__ b4, float* __restrict__ out2) {
    int wid = threadIdx.x >> 6, lane = threadIdx.x & 63;
    int mt = blockIdx.x >> 6, nt = blockIdx.x & 63;   // 8 x 64 tiles of 16x16
    int m0 = mt * 16, n0 = nt * 16;
    int row = lane & 15, kg = lane >> 4;

    const u16* pa = cat + (m0 + row) * NCAT + wid * 1344 + kg * 8;
    const u16* pb = W4b + (n0 + row) * NCAT + wid * 1344 + kg * 8;

    f32x4 acc = {0.f, 0.f, 0.f, 0.f};
    for (int k = 0; k < 1344; k += 32)
        acc = __builtin_amdgcn_mfma_f32_16x16x32_bf16(*(const bf16x8*)(pa + k),
                                                      *(const bf16x8*)(pb + k), acc, 0, 0, 0);

    int col = lane & 15, rbase = (lane >> 4) * 4;
    __shared__ float qs[4][64];
    if (wid == 1) {
#pragma unroll
        for (int r = 0; r < 4; ++r) qs[r][lane] = acc[r];
    }
    __syncthreads();
    if (wid == 0) {
        float bb = b4[n0 + col];
#pragma unroll
        for (int r = 0; r < 4; ++r)
            out2[(m0 + rbase + r) * NFEAT + n0 + col] = fmaxf(acc[r] + qs[r][lane] + bb, 0.f);
    }
}

// ---------------------------------------------------------------------------
extern "C" void kernel_launch(void* const* d_in, const int* in_sizes, int n_in,
                              void* d_out, int out_size, void* d_ws, size_t ws_size,
                              hipStream_t stream) {
    (void)in_sizes; (void)n_in; (void)out_size; (void)ws_size;
    const float* vf      = (const float*)d_in[3];
    const float* sen_fea = (const float*)d_in[4];
    const float* loc     = (const float*)d_in[5];
    const int*   vmask   = (const int*)d_in[7];
    const float* W1 = (const float*)d_in[8];
    const float* b1 = (const float*)d_in[9];
    const float* W2 = (const float*)d_in[10];
    const float* b2 = (const float*)d_in[11];
    const float* W3 = (const float*)d_in[12];
    const float* b3 = (const float*)d_in[13];
    const float* W4 = (const float*)d_in[14];
    const float* b4 = (const float*)d_in[15];

    float* out0 = (float*)d_out;                 // visual_fea copy: 128*256*1024
    float* out1 = out0 + (size_t)BS * T * D;     // sen_fea copy:    128*1024
    float* out2 = out1 + (size_t)BS * D;         // feature:         128*1024

    char* w = (char*)d_ws;
    float* pgv  = (float*)(w);                                // 4 MB
    float* pseg = (float*)(w + 4194304);                      // 4 MB
    u16*   cat  = (u16*)  (w + 2 * 4194304);                  // 688128 B
    u16*   lv   = (u16*)  (w + 2 * 4194304 + 688128);         // 262144 B
    u16*   W1b  = (u16*)  (w + 2 * 4194304 + 950272);         // 1 MB
    u16*   W2b  = (u16*)  (w + 2 * 4194304 + 950272 + 1048576);
    u16*   W4b  = (u16*)  (w + 2 * 4194304 + 950272 + 2097152);  // 5.25 MB

    ka_copy_pool_w<<<4736, 256, 0, stream>>>(vf, out0, vmask, loc, W1, W2, W4,
                                             W1b, W2b, W4b, pgv, pseg);
    k2_build<<<BS, 256, 0, stream>>>(sen_fea, loc, W3, b3, vmask, pgv, pseg, lv, cat, out1);
    k3_vs<<<256, 128, 0, stream>>>(lv, cat, W1b, b1, W2b, b2, cat);
    k4_feat<<<512, 128, 0, stream>>>(cat, W4b, b4, out2);
}